// Round 7
// baseline (351.500 us; speedup 1.0000x reference)
//
#include <hip/hip_runtime.h>
#include <stdint.h>

// SparseConv2D as DENSE f16 MFMA GEMM: out[f,hw] = relu(W[f,:] @ X[:,hw] + b[f]).
// R12: R11 passed but spilled (~170MB excess WRITE, VGPR split 64/64) in the
// region where hold[16] stayed live across an inlined compute_half. Third
// spill from reg-held cross-strip prefetch -> delete it. Also explains R6:
// acc=64 AGPR + 60 VGPR = 124/128, zero headroom, compiler couldn't pipeline
// A-loads -> latency-bound. R12 keeps acc=32 (R11's wave tile 64Mx32N) and
// stages strip 1 global->8-reg-transient->ds_write directly into buf1, placed
// BEFORE epilogue-0 (store latency overlap), 2 barriers total. Worst-point
// pressure ~50 arch + 32 acc -> no spill even at a 64/64 split; ~40 regs of
// headroom for the compiler to batch A-fragment L2 loads (the R6 limiter).
// All math (B addr, XOR swizzle, C/D map, prep_w) verbatim from R11 (passed).

#define NF 512
#define NC 512
#define HW 65536
#define SN 32  // hw columns per strip; block covers 2 strips = 64

typedef _Float16 f16x8 __attribute__((ext_vector_type(8)));
typedef float f32x4 __attribute__((ext_vector_type(4)));

// prep: masked fp32 W -> fragment-linear f16.
// wpk[((t*16+ks)*64+lane)*8 + j] = W[t*16+(lane&15)][ks*32+(lane>>4)*8+j]
__global__ __launch_bounds__(256) void prep_w(const float* __restrict__ kern,
                                              _Float16* __restrict__ wpk) {
  const int idx = blockIdx.x * 256 + threadIdx.x;  // 0..32767
  const int lane = idx & 63;
  const int ks = (idx >> 6) & 15;
  const int t = idx >> 10;
  const int row = t * 16 + (lane & 15);
  const int col = ks * 32 + (lane >> 4) * 8;
  const float4 v0 = *(const float4*)(kern + (size_t)row * NC + col);
  const float4 v1 = *(const float4*)(kern + (size_t)row * NC + col + 4);
  f16x8 o;
  o[0] = (_Float16)v0.x; o[1] = (_Float16)v0.y;
  o[2] = (_Float16)v0.z; o[3] = (_Float16)v0.w;
  o[4] = (_Float16)v1.x; o[5] = (_Float16)v1.y;
  o[6] = (_Float16)v1.z; o[7] = (_Float16)v1.w;
  *(f16x8*)(wpk + (size_t)idx * 8) = o;
}

__device__ __forceinline__ void compute_half(const _Float16* __restrict__ ap,
                                             const _Float16* __restrict__ bufp,
                                             int bb0, int bb1, int bx0, int bx1,
                                             int l4, int ks0, f32x4 acc[4][2]) {
#pragma unroll
  for (int kk = 0; kk < 8; ++kk) {
    const int ks = ks0 + kk;
    f16x8 a[4], b[2];
#pragma unroll
    for (int mt = 0; mt < 4; ++mt)
      a[mt] = *(const f16x8*)(ap + mt * 8192 + ks * 512);
    b[0] = *(const f16x8*)((const char*)bufp + bb0 + (((ks * 4 + l4) ^ bx0) << 4));
    b[1] = *(const f16x8*)((const char*)bufp + bb1 + (((ks * 4 + l4) ^ bx1) << 4));
#pragma unroll
    for (int nt = 0; nt < 2; ++nt)
#pragma unroll
      for (int mt = 0; mt < 4; ++mt)
        acc[mt][nt] = __builtin_amdgcn_mfma_f32_16x16x32_f16(a[mt], b[nt],
                                                             acc[mt][nt], 0, 0, 0);
  }
}

__device__ __forceinline__ void epilogue(const f32x4 acc[4][2],
                                         const float* __restrict__ bias,
                                         float* __restrict__ out, int f0,
                                         int col0) {
#pragma unroll
  for (int mt = 0; mt < 4; ++mt) {
#pragma unroll
    for (int r = 0; r < 4; ++r) {
      const int f = f0 + mt * 16 + r;  // f0 = wave*64 + l4*4
      const float bv = bias[f];
      float* op = out + (size_t)f * HW + col0;
      op[0] = fmaxf(acc[mt][0][r] + bv, 0.f);   // nt=0: n = ln
      op[16] = fmaxf(acc[mt][1][r] + bv, 0.f);  // nt=1: n = 16+ln
    }
  }
}

// stage one 8-float chunk: global (stride HW) -> f16x8 -> one ds_write_b128
__device__ __forceinline__ void stage8(const float* __restrict__ xp, int c0,
                                       char* __restrict__ rowb, int key) {
  f16x8 p;
#pragma unroll
  for (int u = 0; u < 8; ++u) p[u] = (_Float16)xp[(size_t)(c0 + u) * HW];
  *(f16x8*)(rowb + ((((c0 >> 3) ^ key)) << 4)) = p;
}

__global__ __launch_bounds__(512, 4) void spmm_mfma(
    const float* __restrict__ X, const _Float16* __restrict__ Wpk,
    const float* __restrict__ bias, float* __restrict__ out) {
  __shared__ __align__(16) _Float16 xt[2][SN * NC];  // 2 x 32 KiB

  const int tid = threadIdx.x;
  const int wave = tid >> 6;  // 0..7: m-range [wave*64, wave*64+64)
  const int lane = tid & 63;
  const int ln = lane & 15, l4 = lane >> 4;
  const int hwb = blockIdx.x * (2 * SN);

  // staging ownership: row n = tid&31, c-range [(tid>>5)*32, +32)
  const int sn = tid & 31;
  const int sc = (tid >> 5) * 32;
  const float* xp0 = X + hwb + sn;
  const float* xp1 = xp0 + SN;
  char* row0 = (char*)&xt[0][0] + sn * (NC * 2);
  char* row1 = (char*)&xt[1][0] + sn * (NC * 2);

  // B addressing: rows n = ln and 16+ln of the 32-row strip
  const int bb0 = ln * (NC * 2);
  const int bb1 = (16 + ln) * (NC * 2);
  const int bx0 = ln;
  const int bx1 = 16 + ln;

  // A base: wave covers m16-tiles [wave*4, wave*4+4)
  const _Float16* ap = Wpk + (size_t)wave * 32768 + (size_t)lane * 8;

  // ---- stage strip 0 into buf0 ----
#pragma unroll
  for (int j = 0; j < 4; ++j) stage8(xp0, sc + j * 8, row0, sn);
  __syncthreads();

  f32x4 acc[4][2] = {};

  // ---- strip 0 compute ----
  compute_half(ap, &xt[0][0], bb0, bb1, bx0, bx1, l4, 0, acc);
  compute_half(ap, &xt[0][0], bb0, bb1, bx0, bx1, l4, 8, acc);

  // ---- stage strip 1 into buf1 (buf1 unread until next barrier), then
  //      strip-0 epilogue: store latency overlaps the staging loads ----
#pragma unroll
  for (int j = 0; j < 4; ++j) stage8(xp1, sc + j * 8, row1, sn);

  epilogue(acc, bias, out, wave * 64 + l4 * 4, hwb + ln);

  __syncthreads();

  // ---- strip 1 ----
#pragma unroll
  for (int mt = 0; mt < 4; ++mt)
#pragma unroll
    for (int nt = 0; nt < 2; ++nt) acc[mt][nt] = (f32x4){0.f, 0.f, 0.f, 0.f};

  compute_half(ap, &xt[1][0], bb0, bb1, bx0, bx1, l4, 0, acc);
  compute_half(ap, &xt[1][0], bb0, bb1, bx0, bx1, l4, 8, acc);
  epilogue(acc, bias, out, wave * 64 + l4 * 4, hwb + SN + ln);
}

extern "C" void kernel_launch(void* const* d_in, const int* in_sizes, int n_in,
                              void* d_out, int out_size, void* d_ws, size_t ws_size,
                              hipStream_t stream) {
  const float* X = (const float*)d_in[0];     // (1, 512, 256, 256) fp32
  const float* kern = (const float*)d_in[1];  // (512, 512) fp32, pre-masked
  // d_in[2] = mask: redundant (kernel already zeroed where mask false)
  const float* bias = (const float*)d_in[3];  // (512,) fp32
  float* out = (float*)d_out;

  _Float16* wpk = (_Float16*)d_ws;  // 512 KB fragment-packed f16 W

  prep_w<<<NF * NC / 8 / 256, 256, 0, stream>>>(kern, wpk);
  spmm_mfma<<<HW / (2 * SN), 512, 0, stream>>>(X, wpk, bias, out);
}

// Round 8
// 283.348 us; speedup vs baseline: 1.2405x; 1.2405x over previous
//
#include <hip/hip_runtime.h>
#include <stdint.h>

// SparseConv2D as DENSE f16 MFMA GEMM: out[f,hw] = relu(W[f,:] @ X[:,hw] + b[f]).
// R13: R12 proved the spill is structural at the 128-reg cap ((512,4)): with
// acc=32 in VGPRs the allocator still lands at 64 arch regs + ~80 dwords of
// scratch (WRITE 301MB vs 131 expected), while R6's tight 124/128 pack had
// zero headroom to pipeline A-loads (MfmaUtil 10.7, latency-bound). This
// family is pinned between spill and zero-ILP at 128 regs -> trade occupancy
// for headroom: __launch_bounds__(512,2) = 256-reg cap, 1 block/CU.
//  - block: all 512 M x 128 N (two 64-col strips), grid 512 = 2 blocks/CU
//  - LDS: 2 x 64 KiB double buffer (128 KiB total, m201-proven size)
//  - strip-1 staging (R12's stage8) issued BETWEEN strip-0's compute halves:
//    HBM latency hides under 128 MFMAs; X read exactly once
//  - wave tile 64Mx64N, acc[4][4]=64; frags a[4]+b[4]; ~130 live regs < 256
//  - compute/epilogue/A-pack verbatim from passed R6/R11/R12; swizzle key
//    widened to 6 bits (n&63) for the 64-row strip (same per-row bijection)

#define NF 512
#define NC 512
#define HW 65536
#define SN 64  // hw columns per strip; block covers 2 strips = 128

typedef _Float16 f16x8 __attribute__((ext_vector_type(8)));
typedef float f32x4 __attribute__((ext_vector_type(4)));

// prep: masked fp32 W -> fragment-linear f16.
// wpk[((t*16+ks)*64+lane)*8 + j] = W[t*16+(lane&15)][ks*32+(lane>>4)*8+j]
__global__ __launch_bounds__(256) void prep_w(const float* __restrict__ kern,
                                              _Float16* __restrict__ wpk) {
  const int idx = blockIdx.x * 256 + threadIdx.x;  // 0..32767
  const int lane = idx & 63;
  const int ks = (idx >> 6) & 15;
  const int t = idx >> 10;
  const int row = t * 16 + (lane & 15);
  const int col = ks * 32 + (lane >> 4) * 8;
  const float4 v0 = *(const float4*)(kern + (size_t)row * NC + col);
  const float4 v1 = *(const float4*)(kern + (size_t)row * NC + col + 4);
  f16x8 o;
  o[0] = (_Float16)v0.x; o[1] = (_Float16)v0.y;
  o[2] = (_Float16)v0.z; o[3] = (_Float16)v0.w;
  o[4] = (_Float16)v1.x; o[5] = (_Float16)v1.y;
  o[6] = (_Float16)v1.z; o[7] = (_Float16)v1.w;
  *(f16x8*)(wpk + (size_t)idx * 8) = o;
}

__device__ __forceinline__ void compute_half(const _Float16* __restrict__ ap,
                                             const _Float16* __restrict__ bufp,
                                             const int* __restrict__ bb,
                                             int l4, int ks0, f32x4 acc[4][4]) {
#pragma unroll
  for (int kk = 0; kk < 8; ++kk) {
    const int ks = ks0 + kk;
    f16x8 a[4], b[4];
#pragma unroll
    for (int mt = 0; mt < 4; ++mt)
      a[mt] = *(const f16x8*)(ap + mt * 8192 + ks * 512);
#pragma unroll
    for (int nt = 0; nt < 4; ++nt) {
      // row n = bb[nt]/1024; 6-bit key = n&63; slot = (ks*4+l4) ^ key
      const int key = (bb[nt] >> 10) & 63;
      b[nt] = *(const f16x8*)((const char*)bufp + bb[nt] +
                              (((ks * 4 + l4) ^ key) << 4));
    }
#pragma unroll
    for (int nt = 0; nt < 4; ++nt)
#pragma unroll
      for (int mt = 0; mt < 4; ++mt)
        acc[mt][nt] = __builtin_amdgcn_mfma_f32_16x16x32_f16(a[mt], b[nt],
                                                             acc[mt][nt], 0, 0, 0);
  }
}

__device__ __forceinline__ void epilogue(const f32x4 acc[4][4],
                                         const float* __restrict__ bias,
                                         float* __restrict__ out, int f0,
                                         int col0) {
#pragma unroll
  for (int mt = 0; mt < 4; ++mt) {
#pragma unroll
    for (int r = 0; r < 4; ++r) {
      const int f = f0 + mt * 16 + r;  // f0 = wave*64 + l4*4
      const float bv = bias[f];
      float* op = out + (size_t)f * HW + col0;
#pragma unroll
      for (int nt = 0; nt < 4; ++nt)
        op[nt * 16] = fmaxf(acc[mt][nt][r] + bv, 0.f);
    }
  }
}

// stage one 8-float chunk: global (stride HW) -> f16x8 -> one ds_write_b128
__device__ __forceinline__ void stage8(const float* __restrict__ xp, int c0,
                                       char* __restrict__ rowb, int key) {
  f16x8 p;
#pragma unroll
  for (int u = 0; u < 8; ++u) p[u] = (_Float16)xp[(size_t)(c0 + u) * HW];
  *(f16x8*)(rowb + ((((c0 >> 3) ^ key)) << 4)) = p;
}

__global__ __launch_bounds__(512, 2) void spmm_mfma(
    const float* __restrict__ X, const _Float16* __restrict__ Wpk,
    const float* __restrict__ bias, float* __restrict__ out) {
  __shared__ __align__(16) _Float16 xt[2][SN * NC];  // 2 x 64 KiB

  const int tid = threadIdx.x;
  const int wave = tid >> 6;  // 0..7: m-range [wave*64, wave*64+64)
  const int lane = tid & 63;
  const int ln = lane & 15, l4 = lane >> 4;
  const int hwb = blockIdx.x * (2 * SN);

  // staging ownership: row n = lane, c-range [wave*64, wave*64+64)
  const int sc = wave * 64;
  const float* xp0 = X + hwb + lane;
  const float* xp1 = xp0 + SN;
  char* row0 = (char*)&xt[0][0] + lane * (NC * 2);
  char* row1 = (char*)&xt[1][0] + lane * (NC * 2);

  // B addressing: rows n = nt*16 + ln of the 64-row strip (byte base)
  int bb[4];
#pragma unroll
  for (int nt = 0; nt < 4; ++nt) bb[nt] = (nt * 16 + ln) * (NC * 2);

  // A base: wave covers m16-tiles [wave*4, wave*4+4)
  const _Float16* ap = Wpk + (size_t)wave * 32768 + (size_t)lane * 8;

  // ---- stage strip 0 into buf0 ----
#pragma unroll
  for (int j = 0; j < 8; ++j) stage8(xp0, sc + j * 8, row0, lane);
  __syncthreads();

  f32x4 acc[4][4] = {};

  // ---- strip 0 compute; strip-1 staging issued between the halves ----
  compute_half(ap, &xt[0][0], bb, l4, 0, acc);

#pragma unroll
  for (int j = 0; j < 8; ++j) stage8(xp1, sc + j * 8, row1, lane);

  compute_half(ap, &xt[0][0], bb, l4, 8, acc);

  epilogue(acc, bias, out, wave * 64 + l4 * 4, hwb + ln);

  __syncthreads();  // buf1 writes visible; buf0 no longer needed

  // ---- strip 1 ----
#pragma unroll
  for (int mt = 0; mt < 4; ++mt)
#pragma unroll
    for (int nt = 0; nt < 4; ++nt) acc[mt][nt] = (f32x4){0.f, 0.f, 0.f, 0.f};

  compute_half(ap, &xt[1][0], bb, l4, 0, acc);
  compute_half(ap, &xt[1][0], bb, l4, 8, acc);
  epilogue(acc, bias, out, wave * 64 + l4 * 4, hwb + SN + ln);
}

extern "C" void kernel_launch(void* const* d_in, const int* in_sizes, int n_in,
                              void* d_out, int out_size, void* d_ws, size_t ws_size,
                              hipStream_t stream) {
  const float* X = (const float*)d_in[0];     // (1, 512, 256, 256) fp32
  const float* kern = (const float*)d_in[1];  // (512, 512) fp32, pre-masked
  // d_in[2] = mask: redundant (kernel already zeroed where mask false)
  const float* bias = (const float*)d_in[3];  // (512,) fp32
  float* out = (float*)d_out;

  _Float16* wpk = (_Float16*)d_ws;  // 512 KB fragment-packed f16 W

  prep_w<<<NF * NC / 8 / 256, 256, 0, stream>>>(kern, wpk);
  spmm_mfma<<<HW / (2 * SN), 512, 0, stream>>>(X, wpk, bias, out);
}

// Round 9
// 271.825 us; speedup vs baseline: 1.2931x; 1.0424x over previous
//
#include <hip/hip_runtime.h>
#include <stdint.h>

// SparseConv2D as DENSE f16 MFMA GEMM: out[f,hw] = relu(W[f,:] @ X[:,hw] + b[f]).
// R14: R13 steady 125us. Counters: WRITE 181MB (45 dwords/thread scratch,
// VGPR capped at 128) and Little's-law in-flight = ~2 wave-loads/wave ->
// latency-serialized staging, not pipe-bound (MFMA needs 13us, mem 40us).
// Fix: (a) __launch_bounds__(512,1) - occupancy is LDS-bound (2 waves/SIMD)
// anyway, so lift the reg cap -> no spill; (b) batched staging: all 64
// strip loads cvt'd into held f16x8 h[8] (32 regs) BEFORE any ds_write, and
// strip-1's loads issued BEFORE strip-0 compute (T14, peak ~155 regs < 256).
// Everything else verbatim from bench-passed R13 (tile, swizzle, C/D map).

#define NF 512
#define NC 512
#define HW 65536
#define SN 64  // hw columns per strip; block covers 2 strips = 128

typedef _Float16 f16x8 __attribute__((ext_vector_type(8)));
typedef float f32x4 __attribute__((ext_vector_type(4)));

// prep: masked fp32 W -> fragment-linear f16.
// wpk[((t*16+ks)*64+lane)*8 + j] = W[t*16+(lane&15)][ks*32+(lane>>4)*8+j]
__global__ __launch_bounds__(256) void prep_w(const float* __restrict__ kern,
                                              _Float16* __restrict__ wpk) {
  const int idx = blockIdx.x * 256 + threadIdx.x;  // 0..32767
  const int lane = idx & 63;
  const int ks = (idx >> 6) & 15;
  const int t = idx >> 10;
  const int row = t * 16 + (lane & 15);
  const int col = ks * 32 + (lane >> 4) * 8;
  const float4 v0 = *(const float4*)(kern + (size_t)row * NC + col);
  const float4 v1 = *(const float4*)(kern + (size_t)row * NC + col + 4);
  f16x8 o;
  o[0] = (_Float16)v0.x; o[1] = (_Float16)v0.y;
  o[2] = (_Float16)v0.z; o[3] = (_Float16)v0.w;
  o[4] = (_Float16)v1.x; o[5] = (_Float16)v1.y;
  o[6] = (_Float16)v1.z; o[7] = (_Float16)v1.w;
  *(f16x8*)(wpk + (size_t)idx * 8) = o;
}

__device__ __forceinline__ void compute_half(const _Float16* __restrict__ ap,
                                             const _Float16* __restrict__ bufp,
                                             const int* __restrict__ bb,
                                             int l4, int ks0, f32x4 acc[4][4]) {
#pragma unroll
  for (int kk = 0; kk < 8; ++kk) {
    const int ks = ks0 + kk;
    f16x8 a[4], b[4];
#pragma unroll
    for (int mt = 0; mt < 4; ++mt)
      a[mt] = *(const f16x8*)(ap + mt * 8192 + ks * 512);
#pragma unroll
    for (int nt = 0; nt < 4; ++nt) {
      // row n = bb[nt]/1024; 6-bit key = n&63; slot = (ks*4+l4) ^ key
      const int key = (bb[nt] >> 10) & 63;
      b[nt] = *(const f16x8*)((const char*)bufp + bb[nt] +
                              (((ks * 4 + l4) ^ key) << 4));
    }
#pragma unroll
    for (int nt = 0; nt < 4; ++nt)
#pragma unroll
      for (int mt = 0; mt < 4; ++mt)
        acc[mt][nt] = __builtin_amdgcn_mfma_f32_16x16x32_f16(a[mt], b[nt],
                                                             acc[mt][nt], 0, 0, 0);
  }
}

__device__ __forceinline__ void epilogue(const f32x4 acc[4][4],
                                         const float* __restrict__ bias,
                                         float* __restrict__ out, int f0,
                                         int col0) {
#pragma unroll
  for (int mt = 0; mt < 4; ++mt) {
#pragma unroll
    for (int r = 0; r < 4; ++r) {
      const int f = f0 + mt * 16 + r;  // f0 = wave*64 + l4*4
      const float bv = bias[f];
      float* op = out + (size_t)f * HW + col0;
#pragma unroll
      for (int nt = 0; nt < 4; ++nt)
        op[nt * 16] = fmaxf(acc[mt][nt][r] + bv, 0.f);
    }
  }
}

// load 8 c-strided floats (coalesced across lanes) and pack to f16x8
__device__ __forceinline__ f16x8 loadcvt8(const float* __restrict__ xp, int c0) {
  float v[8];
#pragma unroll
  for (int u = 0; u < 8; ++u) v[u] = xp[(size_t)(c0 + u) * HW];
  f16x8 p;
#pragma unroll
  for (int u = 0; u < 8; ++u) p[u] = (_Float16)v[u];
  return p;
}

__global__ __launch_bounds__(512, 1) void spmm_mfma(
    const float* __restrict__ X, const _Float16* __restrict__ Wpk,
    const float* __restrict__ bias, float* __restrict__ out) {
  __shared__ __align__(16) _Float16 xt[2][SN * NC];  // 2 x 64 KiB

  const int tid = threadIdx.x;
  const int wave = tid >> 6;  // 0..7: m-range [wave*64, wave*64+64)
  const int lane = tid & 63;
  const int ln = lane & 15, l4 = lane >> 4;
  const int hwb = blockIdx.x * (2 * SN);

  // staging ownership: row n = lane, c-range [wave*64, wave*64+64)
  const int sc = wave * 64;
  const float* xp0 = X + hwb + lane;
  const float* xp1 = xp0 + SN;
  char* row0 = (char*)&xt[0][0] + lane * (NC * 2);
  char* row1 = (char*)&xt[1][0] + lane * (NC * 2);

  // B addressing: rows n = nt*16 + ln of the 64-row strip (byte base)
  int bb[4];
#pragma unroll
  for (int nt = 0; nt < 4; ++nt) bb[nt] = (nt * 16 + ln) * (NC * 2);

  // A base: wave covers m16-tiles [wave*4, wave*4+4)
  const _Float16* ap = Wpk + (size_t)wave * 32768 + (size_t)lane * 8;

  // ---- stage strip 0 into buf0: all 64 loads batched, then 8 writes ----
  {
    f16x8 h0[8];
#pragma unroll
    for (int j = 0; j < 8; ++j) h0[j] = loadcvt8(xp0, sc + j * 8);
#pragma unroll
    for (int j = 0; j < 8; ++j) {
      const int c0 = sc + j * 8;
      *(f16x8*)(row0 + ((((c0 >> 3) ^ lane)) << 4)) = h0[j];
    }
  }
  __syncthreads();

  f32x4 acc[4][4] = {};

  // ---- strip-1 prefetch: 64 loads + cvt held in h1[8] (32 regs, T14) ----
  f16x8 h1[8];
#pragma unroll
  for (int j = 0; j < 8; ++j) h1[j] = loadcvt8(xp1, sc + j * 8);

  compute_half(ap, &xt[0][0], bb, l4, 0, acc);

  // write held strip 1 into buf1 (buf1 unread until the barrier below)
#pragma unroll
  for (int j = 0; j < 8; ++j) {
    const int c0 = sc + j * 8;
    *(f16x8*)(row1 + ((((c0 >> 3) ^ lane)) << 4)) = h1[j];
  }

  compute_half(ap, &xt[0][0], bb, l4, 8, acc);

  epilogue(acc, bias, out, wave * 64 + l4 * 4, hwb + ln);

  __syncthreads();  // buf1 writes visible; buf0 no longer needed

  // ---- strip 1 ----
#pragma unroll
  for (int mt = 0; mt < 4; ++mt)
#pragma unroll
    for (int nt = 0; nt < 4; ++nt) acc[mt][nt] = (f32x4){0.f, 0.f, 0.f, 0.f};

  compute_half(ap, &xt[1][0], bb, l4, 0, acc);
  compute_half(ap, &xt[1][0], bb, l4, 8, acc);
  epilogue(acc, bias, out, wave * 64 + l4 * 4, hwb + SN + ln);
}

extern "C" void kernel_launch(void* const* d_in, const int* in_sizes, int n_in,
                              void* d_out, int out_size, void* d_ws, size_t ws_size,
                              hipStream_t stream) {
  const float* X = (const float*)d_in[0];     // (1, 512, 256, 256) fp32
  const float* kern = (const float*)d_in[1];  // (512, 512) fp32, pre-masked
  // d_in[2] = mask: redundant (kernel already zeroed where mask false)
  const float* bias = (const float*)d_in[3];  // (512,) fp32
  float* out = (float*)d_out;

  _Float16* wpk = (_Float16*)d_ws;  // 512 KB fragment-packed f16 W

  prep_w<<<NF * NC / 8 / 256, 256, 0, stream>>>(kern, wpk);
  spmm_mfma<<<HW / (2 * SN), 512, 0, stream>>>(X, wpk, bias, out);
}